// Round 7
// baseline (38695.514 us; speedup 1.0000x reference)
//
#include <hip/hip_runtime.h>
#include <hip/hip_bf16.h>

#define B_   64
#define T_   2048
#define F_   256
#define H_   512
#define NG   8                    // batch groups, one per XCD (assumed)
#define GR   8                    // batch rows per group
#define NWG  64
#define PKTS 2048                 // GR rows * 256 col-pairs
#define SLOTS 4

typedef __attribute__((ext_vector_type(8))) short bfrag;   // 8 bf16 (MFMA A/B)
typedef __attribute__((ext_vector_type(4))) int   int4v;
typedef __attribute__((ext_vector_type(2))) int   int2v;   // 8B packet {payload, tag}
typedef __attribute__((ext_vector_type(4))) float f32x4;
typedef __attribute__((ext_vector_type(4))) float float4_t;

__device__ __forceinline__ float fsig(float x)  { return 1.0f / (1.0f + __expf(-x)); }
__device__ __forceinline__ float ftanh(float x) { return 2.0f / (1.0f + __expf(-2.0f * x)) - 1.0f; }
__device__ __forceinline__ short f2bf(float f) {
  __hip_bfloat16 h = __float2bfloat16(f);
  return __builtin_bit_cast(short, h);
}

// ---- MALL-path (sc0 sc1: bypass L1+L2) ----
__device__ __forceinline__ int2v gload8_cc(const void* p) {
  int2v r;
  asm volatile("global_load_dwordx2 %0, %1, off sc0 sc1" : "=v"(r) : "v"(p));
  return r;
}
__device__ __forceinline__ void gstore8_cc(void* p, int2v d) {
  asm volatile("global_store_dwordx2 %0, %1, off sc0 sc1" :: "v"(p), "v"(d));
}
__device__ __forceinline__ void gstore4_cc(void* p, int d) {
  asm volatile("global_store_dword %0, %1, off sc0 sc1" :: "v"(p), "v"(d));
}
__device__ __forceinline__ int gload_flag(const void* p) {
  int r;
  asm volatile("global_load_dword %0, %1, off sc0 sc1\n\ts_waitcnt vmcnt(0)"
               : "=v"(r) : "v"(p) : "memory");
  return r;
}
// ---- XCD-L2 path (sc0 only: bypass L1, coherent within one XCD's L2) ----
__device__ __forceinline__ int2v gload8_l2(const void* p) {
  int2v r;
  asm volatile("global_load_dwordx2 %0, %1, off sc0" : "=v"(r) : "v"(p));
  return r;
}
__device__ __forceinline__ void gstore8_l2(void* p, int2v d) {
  asm volatile("global_store_dwordx2 %0, %1, off sc0" :: "v"(p), "v"(d));
}
__device__ __forceinline__ void vm_drain() {
  asm volatile("s_waitcnt vmcnt(0)" ::: "memory");
  __builtin_amdgcn_sched_barrier(0);   // rule #18
}

// ---------------- init: slot-0 packets (both buffers), xcdmap = -1 ----------------
__global__ void lstm_init(const float* __restrict__ z,
                          unsigned long long* __restrict__ fast0,
                          unsigned long long* __restrict__ slow0,
                          int* __restrict__ xcdmap) {
  int i = blockIdx.x * blockDim.x + threadIdx.x;     // 0..16383
  if (i < NWG) xcdmap[i] = -1;
  int g  = i >> 11;
  int P  = i & 2047;
  int r  = P >> 8;
  int pr = P & 255;
  int row = g * GR + r;
  unsigned int lo = (unsigned)(unsigned short)f2bf(z[(size_t)row * H_ + 2 * pr])
                  | ((unsigned)(unsigned short)f2bf(z[(size_t)row * H_ + 2 * pr + 1]) << 16);
  unsigned long long pk = (unsigned long long)lo;    // tag (high dword) = 0
  fast0[(size_t)g * PKTS + P] = pk;
  slow0[(size_t)g * PKTS + P] = pk;
}

// ---------------- persistent LSTM, XCD-local groups ----------------
// Group g (= blockIdx%8, presumed XCD g): batch rows [8g, 8g+8).
// Member mem (= blockIdx/8): h-cols [64*mem, +64), out-cols [32*mem, +32).
// M=8 tile: D rows 4*qq+r valid for qq<2; A rows duplicated via l16&7.
// Handoff: dual-store packets {2 bf16, tag} to fastbuf (sc0, XCD-L2) +
// slowbuf (sc0sc1, MALL). Consumers poll fast iff runtime XCC check passed;
// sticky timeout fallback to slow. Correct under ANY placement (G16).
// 4 slots required: producer may lead consumers by up to 3 steps before
// overwriting a slot a lagging consumer still polls.
__global__ void __launch_bounds__(256, 1)
lstm_persist(const float* __restrict__ x,
             const float* __restrict__ Wih,  const float* __restrict__ Whh,
             const float* __restrict__ bih,  const float* __restrict__ bhh,
             const float* __restrict__ Wlin, const float* __restrict__ blin,
             float* __restrict__ out,
             int2v* __restrict__ fastp, int2v* __restrict__ slowp,
             int* __restrict__ xcdmap)
{
  __shared__ char smem[8192 + 32768 + 16];   // h-tile | W_lin slice | flag
  const int hOff = 0, wOff = 8192, fOff = 8192 + 32768;

  const int wg  = blockIdx.x;
  const int g   = wg & 7;            // group (presumed XCD)
  const int mem = wg >> 3;           // member 0..7
  const int tid = threadIdx.x;
  const int wv  = tid >> 6;
  const int l   = tid & 63;
  const int l16 = l & 15;
  const int qq  = l >> 4;

  // ---- publish XCC id; decide fast/slow path ----
  const int xcc = __builtin_amdgcn_s_getreg(6164);   // hwreg(HW_REG_XCC_ID=20,0,4)
  if (tid == 0) gstore4_cc(&xcdmap[wg], xcc);
  vm_drain();
  if (wv == 0) {
    int other = xcc;
    bool got = (l >= NG);
    for (int it = 0; it < 200000; ++it) {
      if (!got) {
        int v = gload_flag(&xcdmap[g + NG * l]);
        if (v != -1) { other = v; got = true; }
      }
      if (__all(got)) break;
      __builtin_amdgcn_s_sleep(1);
    }
    int ok = __all(got && (other == xcc)) ? 1 : 0;
    if (l == 0) *(int*)(smem + fOff) = ok;
  }

  // ---- stage W_lin slice (cols 32*mem..+32, K=512) to LDS, swizzled ----
  {
    const int oc = tid >> 3;
    const float* src = Wlin + (size_t)(32 * mem + oc) * H_ + (tid & 7) * 64;
    char* dst = smem + wOff + oc * 1024;
    #pragma unroll
    for (int i = 0; i < 8; ++i) {
      bfrag tmp;
      #pragma unroll
      for (int e = 0; e < 8; ++e) tmp[e] = f2bf(src[i * 8 + e]);
      *(int4v*)(dst + ((((tid & 7) * 128) + i * 16) ^ ((oc & 7) << 4))) =
          __builtin_bit_cast(int4v, tmp);
    }
  }

  // ---- persistent weight fragments ----
  bfrag WH[4][16], WI[4][8];
  float bs[4];
  #pragma unroll
  for (int q = 0; q < 4; ++q) {
    const int grow = q * H_ + 64 * mem + 16 * wv + l16;
    #pragma unroll
    for (int kt = 0; kt < 16; ++kt) {
      const float* s = Whh + (size_t)grow * H_ + kt * 32 + qq * 8;
      bfrag w;
      #pragma unroll
      for (int e = 0; e < 8; ++e) w[e] = f2bf(s[e]);
      WH[q][kt] = w;
    }
    #pragma unroll
    for (int kt = 0; kt < 8; ++kt) {
      const float* s = Wih + (size_t)grow * F_ + kt * 32 + qq * 8;
      bfrag w;
      #pragma unroll
      for (int e = 0; e < 8; ++e) w[e] = f2bf(s[e]);
      WI[q][kt] = w;
    }
    bs[q] = bih[grow] + bhh[grow];
  }
  const float blc = (wv < 2) ? blin[32 * mem + 16 * wv + l16] : 0.f;

  float c4[4] = {0.f, 0.f, 0.f, 0.f};
  __syncthreads();
  bool useFast = (*(int*)(smem + fOff) != 0);

  const int P0 = (tid >> 5) * 256 + (tid & 31);    // poll base: row tid/32, pair tid%32

  for (int t = 0; t < T_; ++t) {
    // ---- A: x-part of gates (h-independent shadow work, absorbs skew) ----
    f32x4 acc[4] = {{0,0,0,0},{0,0,0,0},{0,0,0,0},{0,0,0,0}};
    {
      const float* xr = x + ((size_t)(GR * g + (l16 & 7)) * T_ + t) * F_ + qq * 8;
      #pragma unroll
      for (int kt = 0; kt < 8; ++kt) {
        float4_t xa = *(const float4_t*)(xr + kt * 32);
        float4_t xb = *(const float4_t*)(xr + kt * 32 + 4);
        bfrag a;
        #pragma unroll
        for (int e = 0; e < 4; ++e) { a[e] = f2bf(xa[e]); a[4 + e] = f2bf(xb[e]); }
        #pragma unroll
        for (int q = 0; q < 4; ++q)
          acc[q] = __builtin_amdgcn_mfma_f32_16x16x32_bf16(a, WI[q][kt], acc[q], 0, 0, 0);
      }
    }

    // ---- B: poll h_t packets, slot t&3 ----
    const size_t slotOff = (size_t)((t & 3) * NG + g) * PKTS;
    const int2v* fb = fastp + slotOff + P0;
    const int2v* sb = slowp + slotOff + P0;
    int2v pv[8];
    int iter = 0;
    while (true) {
      if (useFast) {
        #pragma unroll
        for (int j = 0; j < 8; ++j) pv[j] = gload8_l2(fb + 32 * j);
      } else {
        #pragma unroll
        for (int j = 0; j < 8; ++j) pv[j] = gload8_cc(sb + 32 * j);
      }
      vm_drain();
      bool ok = true;
      #pragma unroll
      for (int j = 0; j < 8; ++j) ok &= (pv[j].y == t);
      if (__all(ok)) break;
      if (useFast && ++iter > 30000) useFast = false;   // sticky fallback
      __builtin_amdgcn_s_sleep(1);
    }
    __syncthreads();   // prior iter's LDS reads done

    // ---- C: stage h-tile [8][512]bf16 to LDS, swizzled ----
    {
      const int r = tid >> 5;
      char* base = smem + hOff + r * 1024;
      #pragma unroll
      for (int j = 0; j < 8; ++j)
        *(int*)(base + ((4 * ((tid & 31) + 32 * j)) ^ ((r & 7) << 4))) = pv[j].x;
    }
    __syncthreads();

    // ---- D: gates h-part + fused out[t-1] GEMM ----
    f32x4 oacc = {blc, blc, blc, blc};
    #pragma unroll
    for (int kt = 0; kt < 16; ++kt) {
      bfrag a = *(const bfrag*)(smem + hOff + (l16 & 7) * 1024 +
                                ((kt * 64 + qq * 16) ^ ((l16 & 7) << 4)));
      #pragma unroll
      for (int q = 0; q < 4; ++q)
        acc[q] = __builtin_amdgcn_mfma_f32_16x16x32_bf16(a, WH[q][kt], acc[q], 0, 0, 0);
      if (wv < 2) {
        const int oc = 16 * wv + l16;
        bfrag wl = *(const bfrag*)(smem + wOff + oc * 1024 +
                                   ((kt * 64 + qq * 16) ^ ((oc & 7) << 4)));
        oacc = __builtin_amdgcn_mfma_f32_16x16x32_bf16(a, wl, oacc, 0, 0, 0);
      }
    }

    // ---- E: activations, state, dual packet stores (fire & forget) ----
    const size_t nxtOff = (size_t)(((t + 1) & 3) * NG + g) * PKTS;
    int2v* fs = fastp + nxtOff;
    int2v* ss = slowp + nxtOff;
    #pragma unroll
    for (int r = 0; r < 4; ++r) {
      float hn = 0.f;
      if (qq < 2) {
        float iv = fsig(acc[0][r] + bs[0]);
        float fv = fsig(acc[1][r] + bs[1]);
        float gv = ftanh(acc[2][r] + bs[2]);
        float ov = fsig(acc[3][r] + bs[3]);
        float cn = fv * c4[r] + iv * gv;
        c4[r] = cn;
        hn = ov * ftanh(cn);
      }
      int hb = (int)(unsigned short)f2bf(hn);
      int pu = __shfl_xor(hb, 1);
      if (qq < 2 && (l16 & 1) == 0) {
        int2v pk;
        pk.x = (hb & 0xffff) | (pu << 16);
        pk.y = t + 1;
        const int P = (4 * qq + r) * 256 + (32 * mem + 8 * wv + (l16 >> 1));
        gstore8_l2(fs + P, pk);
        gstore8_cc(ss + P, pk);
      }
    }

    // ---- F: out[t-1] store (cached) ----
    if (t > 0 && wv < 2 && qq < 2) {
      #pragma unroll
      for (int r = 0; r < 4; ++r)
        out[(size_t)(GR * g + 4 * qq + r) * T_ * F_ + (size_t)(t - 1) * F_ +
            32 * mem + 16 * wv + l16] = oacc[r];
    }
  }

  // ---- tail: out[T-1] from h_T (slot 0, tag T_) ----
  {
    const size_t slotOff = (size_t)((T_ & 3) * NG + g) * PKTS;
    const int2v* fb = fastp + slotOff + P0;
    const int2v* sb = slowp + slotOff + P0;
    int2v pv[8];
    int iter = 0;
    while (true) {
      if (useFast) {
        #pragma unroll
        for (int j = 0; j < 8; ++j) pv[j] = gload8_l2(fb + 32 * j);
      } else {
        #pragma unroll
        for (int j = 0; j < 8; ++j) pv[j] = gload8_cc(sb + 32 * j);
      }
      vm_drain();
      bool ok = true;
      #pragma unroll
      for (int j = 0; j < 8; ++j) ok &= (pv[j].y == T_);
      if (__all(ok)) break;
      if (useFast && ++iter > 30000) useFast = false;
      __builtin_amdgcn_s_sleep(1);
    }
    __syncthreads();
    {
      const int r = tid >> 5;
      char* base = smem + hOff + r * 1024;
      #pragma unroll
      for (int j = 0; j < 8; ++j)
        *(int*)(base + ((4 * ((tid & 31) + 32 * j)) ^ ((r & 7) << 4))) = pv[j].x;
    }
    __syncthreads();

    if (wv < 2) {
      f32x4 oacc = {blc, blc, blc, blc};
      #pragma unroll
      for (int kt = 0; kt < 16; ++kt) {
        bfrag a = *(const bfrag*)(smem + hOff + (l16 & 7) * 1024 +
                                  ((kt * 64 + qq * 16) ^ ((l16 & 7) << 4)));
        const int oc = 16 * wv + l16;
        bfrag wl = *(const bfrag*)(smem + wOff + oc * 1024 +
                                   ((kt * 64 + qq * 16) ^ ((oc & 7) << 4)));
        oacc = __builtin_amdgcn_mfma_f32_16x16x32_bf16(a, wl, oacc, 0, 0, 0);
      }
      if (qq < 2) {
        #pragma unroll
        for (int r = 0; r < 4; ++r)
          out[(size_t)(GR * g + 4 * qq + r) * T_ * F_ + (size_t)(T_ - 1) * F_ +
              32 * mem + 16 * wv + l16] = oacc[r];
      }
    }
  }
}

extern "C" void kernel_launch(void* const* d_in, const int* in_sizes, int n_in,
                              void* d_out, int out_size, void* d_ws, size_t ws_size,
                              hipStream_t stream) {
  const float* z    = (const float*)d_in[0];
  const float* x    = (const float*)d_in[1];
  const float* Wih  = (const float*)d_in[2];
  const float* Whh  = (const float*)d_in[3];
  const float* bih  = (const float*)d_in[4];
  const float* bhh  = (const float*)d_in[5];
  const float* Wlin = (const float*)d_in[6];
  const float* blin = (const float*)d_in[7];
  float* out = (float*)d_out;

  const size_t bufBytes = (size_t)SLOTS * NG * PKTS * 8;   // 512 KB each
  int2v* fastp = (int2v*)d_ws;
  int2v* slowp = (int2v*)((char*)d_ws + bufBytes);
  int*   xcdmap = (int*)((char*)d_ws + 2 * bufBytes);

  lstm_init<<<64, 256, 0, stream>>>(z, (unsigned long long*)fastp,
                                    (unsigned long long*)slowp, xcdmap);
  lstm_persist<<<NWG, 256, 0, stream>>>(x, Wih, Whh, bih, bhh, Wlin, blin, out,
                                        fastp, slowp, xcdmap);
}

// Round 8
// 36527.386 us; speedup vs baseline: 1.0594x; 1.0594x over previous
//
#include <hip/hip_runtime.h>
#include <hip/hip_bf16.h>

#define B_   64
#define T_   2048
#define F_   256
#define H_   512
#define GB   4                    // batch groups (16 rows each)
#define GG   8                    // gate-split WGs per group
#define NWG  (GB*GG)              // 32
#define PKTS_PER_GROUP 4096       // 16 rows * 256 col-pairs
#define SLOTS 4
#define GUARD_CAP 150000

typedef __attribute__((ext_vector_type(8))) short bfrag;   // 8 bf16 (MFMA A/B)
typedef __attribute__((ext_vector_type(4))) int   int4v;
typedef __attribute__((ext_vector_type(2))) int   int2v;   // 8B packet {payload, tag}
typedef __attribute__((ext_vector_type(4))) float f32x4;
typedef __attribute__((ext_vector_type(4))) float float4_t;

__device__ __forceinline__ float fsig(float x)  { return 1.0f / (1.0f + __expf(-x)); }
__device__ __forceinline__ float ftanh(float x) { return 2.0f / (1.0f + __expf(-2.0f * x)) - 1.0f; }
__device__ __forceinline__ short f2bf(float f) {
  __hip_bfloat16 h = __float2bfloat16(f);
  return __builtin_bit_cast(short, h);
}

// ---- MALL-path (sc0 sc1: bypass L1+L2) ----
__device__ __forceinline__ int2v gload8_cc(const void* p) {
  int2v r;
  asm volatile("global_load_dwordx2 %0, %1, off sc0 sc1" : "=v"(r) : "v"(p));
  return r;
}
__device__ __forceinline__ void gstore8_cc(void* p, int2v d) {
  asm volatile("global_store_dwordx2 %0, %1, off sc0 sc1" :: "v"(p), "v"(d));
}
__device__ __forceinline__ void gstore4_cc(void* p, int d) {
  asm volatile("global_store_dword %0, %1, off sc0 sc1" :: "v"(p), "v"(d));
}
__device__ __forceinline__ int gload_flag(const void* p) {
  int r;
  asm volatile("global_load_dword %0, %1, off sc0 sc1\n\ts_waitcnt vmcnt(0)"
               : "=v"(r) : "v"(p) : "memory");
  return r;
}
// ---- XCD-L2 path (sc0 only) ----
__device__ __forceinline__ void gstore4_l2(void* p, int d) {
  asm volatile("global_store_dword %0, %1, off sc0" :: "v"(p), "v"(d));
}
__device__ __forceinline__ int gload_flag_l2(const void* p) {
  int r;
  asm volatile("global_load_dword %0, %1, off sc0\n\ts_waitcnt vmcnt(0)"
               : "=v"(r) : "v"(p) : "memory");
  return r;
}
__device__ __forceinline__ void vm_drain() {
  asm volatile("s_waitcnt vmcnt(0)" ::: "memory");
  __builtin_amdgcn_sched_barrier(0);   // rule #18
}

// ================= EXPERIMENTS (ws-only, bounded, zeroed each launch) =========

// E1: pure MALL ping-pong, 2 WGs, 2048 rounds. dur/2048 = 2x one-way handoff.
__global__ void exp_mall_pp(int* e) {
  const int wg = blockIdx.x;
  const int l  = threadIdx.x;
  int guard = 0;
  if (wg == 0) {
    for (int t = 1; t <= 2048; ++t) {
      if (l == 0) gstore4_cc(&e[0], t);
      while (gload_flag(&e[16]) < t) { if (++guard > GUARD_CAP) return; }
    }
  } else {
    for (int t = 1; t <= 2048; ++t) {
      while (gload_flag(&e[0]) < t) { if (++guard > GUARD_CAP) return; }
      if (l == 0) gstore4_cc(&e[16], t);
    }
  }
}

// E2: R2-topology 64-WG flag barrier (no payload), 2048 rounds.
__global__ void exp_b64(int* f) {
  const int g = blockIdx.x;
  const int l = threadIdx.x;
  int guard = 0;
  for (int t = 1; t <= 2048; ++t) {
    if (l == 0) gstore4_cc(&f[g * 16], t);
    while (true) {
      int v = gload_flag(&f[l * 16]);
      if (__all(v >= t)) break;
      if (++guard > 4 * GUARD_CAP) return;
    }
  }
}

// E3: sc0-only ping-pong between blockIdx 0 and 8 (presumed same XCD).
// Fast => same-XCD L2 handoff works; guard-exit (~long) => it doesn't.
__global__ void exp_l2_pp(int* e) {
  const int wg = blockIdx.x;
  const int l  = threadIdx.x;
  if (wg != 0 && wg != 8) return;
  int guard = 0;
  if (wg == 0) {
    for (int t = 1; t <= 2048; ++t) {
      if (l == 0) gstore4_l2(&e[0], t);
      while (gload_flag_l2(&e[16]) < t) { if (++guard > GUARD_CAP) return; }
    }
  } else {
    for (int t = 1; t <= 2048; ++t) {
      while (gload_flag_l2(&e[0]) < t) { if (++guard > GUARD_CAP) return; }
      if (l == 0) gstore4_l2(&e[16], t);
    }
  }
}

// E4: MALL ping-pong (WG0/WG1) while 62 WGs flood MALL with poll loads.
__global__ void exp_pp_flood(int* e, int* fl) {
  const int wg = blockIdx.x;
  const int l  = threadIdx.x;
  int guard = 0;
  if (wg == 0) {
    bool alive = true;
    for (int t = 1; t <= 2048 && alive; ++t) {
      if (l == 0) gstore4_cc(&e[0], t);
      while (gload_flag(&e[16]) < t) { if (++guard > GUARD_CAP) { alive = false; break; } }
    }
    if (l == 0) gstore4_cc(&e[32], 1);   // done
  } else if (wg == 1) {
    for (int t = 1; t <= 2048; ++t) {
      while (gload_flag(&e[0]) < t) { if (++guard > GUARD_CAP) return; }
      if (l == 0) gstore4_cc(&e[16], t);
    }
  } else {
    for (int i = 0; i < 200000; ++i) {
      (void)gload_flag(&fl[l * 16]);
      if ((i & 63) == 63 && gload_flag(&e[32]) != 0) break;
    }
  }
}

// ---------------- init: slot-0 packets = h_0 = bf16(z); zero experiment region ----
__global__ void lstm_init(const float* __restrict__ z, unsigned long long* __restrict__ pkt0,
                          int* __restrict__ expb) {
  int i = blockIdx.x * blockDim.x + threadIdx.x;     // 0..16383
  if (i < 8192) expb[i] = 0;
  int g  = i >> 12;            // group
  int p  = i & 4095;
  int j  = p >> 8;             // row within group
  int pr = p & 255;            // col pair
  int row = 16 * g + j;
  unsigned int lo = (unsigned)(unsigned short)f2bf(z[(size_t)row * H_ + 2 * pr])
                  | ((unsigned)(unsigned short)f2bf(z[(size_t)row * H_ + 2 * pr + 1]) << 16);
  pkt0[i] = (unsigned long long)lo;                  // tag (high dword) = 0
}

// ---------------- persistent LSTM, batch-grouped (R5 verbatim — best known) ----
__global__ void __launch_bounds__(256, 1)
lstm_persist(const float* __restrict__ x,
             const float* __restrict__ Wih,  const float* __restrict__ Whh,
             const float* __restrict__ bih,  const float* __restrict__ bhh,
             const float* __restrict__ Wlin, const float* __restrict__ blin,
             float* __restrict__ out, int2v* __restrict__ pkt)
{
  __shared__ char smem[49152];   // [0,16K): h-tile [16][512]bf16 swz; [16K,48K): W_lin slice

  const int wg  = blockIdx.x;
  const int b   = wg >> 3;
  const int k   = wg & 7;
  const int tid = threadIdx.x;
  const int wv  = tid >> 6;
  const int l   = tid & 63;
  const int l16 = l & 15;
  const int qq  = l >> 4;
  const int swz = (l16 & 7) << 4;
  const int m4  = qq << 2;                 // D row base (+reg)

  // ---- stage W_lin slice (cols 32k..32k+32, K=512) to LDS, swizzled ----
  {
    const int oc = tid >> 3;               // 0..31
    const float* src = Wlin + (size_t)(32 * k + oc) * H_ + (tid & 7) * 64;
    char* dst = smem + 16384 + oc * 1024;
    #pragma unroll
    for (int i = 0; i < 8; ++i) {
      bfrag tmp;
      #pragma unroll
      for (int e = 0; e < 8; ++e) tmp[e] = f2bf(src[i * 8 + e]);
      *(int4v*)(dst + ((((tid & 7) * 128) + i * 16) ^ ((oc & 7) << 4))) =
          __builtin_bit_cast(int4v, tmp);
    }
  }

  // ---- persistent weight fragments in VGPR ----
  bfrag WH[4][16];   // W_hh: gate q, k-tile kt
  bfrag WI[4][8];    // W_ih
  float bs[4];
  #pragma unroll
  for (int q = 0; q < 4; ++q) {
    const int grow = q * H_ + k * 64 + wv * 16 + l16;   // this lane's gate row
    #pragma unroll
    for (int kt = 0; kt < 16; ++kt) {
      const float* s = Whh + (size_t)grow * H_ + kt * 32 + qq * 8;
      bfrag w;
      #pragma unroll
      for (int e = 0; e < 8; ++e) w[e] = f2bf(s[e]);
      WH[q][kt] = w;
    }
    #pragma unroll
    for (int kt = 0; kt < 8; ++kt) {
      const float* s = Wih + (size_t)grow * F_ + kt * 32 + qq * 8;
      bfrag w;
      #pragma unroll
      for (int e = 0; e < 8; ++e) w[e] = f2bf(s[e]);
      WI[q][kt] = w;
    }
    bs[q] = bih[grow] + bhh[grow];
  }
  const float blc = (wv < 2) ? blin[32 * k + 16 * wv + l16] : 0.f;

  float c4[4] = {0.f, 0.f, 0.f, 0.f};
  __syncthreads();   // W_lin staged

  for (int t = 0; t < T_; ++t) {
    // ---- A: x-part of gates (h-independent shadow work, absorbs group skew) ----
    f32x4 acc[4] = {{0,0,0,0},{0,0,0,0},{0,0,0,0},{0,0,0,0}};
    {
      const float* xr = x + ((size_t)(16 * b + l16) * T_ + t) * F_ + qq * 8;
      #pragma unroll
      for (int kt = 0; kt < 8; ++kt) {
        float4_t xa = *(const float4_t*)(xr + kt * 32);
        float4_t xb = *(const float4_t*)(xr + kt * 32 + 4);
        bfrag a;
        #pragma unroll
        for (int e = 0; e < 4; ++e) { a[e] = f2bf(xa[e]); a[4 + e] = f2bf(xb[e]); }
        #pragma unroll
        for (int q = 0; q < 4; ++q)
          acc[q] = __builtin_amdgcn_mfma_f32_16x16x32_bf16(a, WI[q][kt], acc[q], 0, 0, 0);
      }
    }

    // ---- B: poll h_t packets (slot t&3); lane owns (row j, pair tid), j=0..15 ----
    const int2v* pp = pkt + (size_t)((t & 3) * GB + b) * PKTS_PER_GROUP + tid;
    int2v pv[16];
    while (true) {
      #pragma unroll
      for (int j = 0; j < 16; ++j) pv[j] = gload8_cc(pp + j * 256);
      vm_drain();                            // also bounds in-flight pkt stores
      bool ok = true;
      #pragma unroll
      for (int j = 0; j < 16; ++j) ok &= (pv[j].y == t);
      if (__all(ok)) break;
      __builtin_amdgcn_s_sleep(2);
    }
    __syncthreads();    // all waves done with prior iter's LDS reads

    // ---- C: build h-tile in LDS (swizzled) ----
    #pragma unroll
    for (int j = 0; j < 16; ++j)
      *(int*)(smem + j * 1024 + ((tid * 4) ^ ((j & 7) << 4))) = pv[j].x;
    __syncthreads();

    // ---- D: gates h-part + fused out[t-1] (waves 0,1 own the 2 out n-tiles) ----
    f32x4 oacc = {blc, blc, blc, blc};
    #pragma unroll
    for (int kt = 0; kt < 16; ++kt) {
      bfrag a = *(const bfrag*)(smem + l16 * 1024 + ((kt * 64 + qq * 16) ^ swz));
      #pragma unroll
      for (int q = 0; q < 4; ++q)
        acc[q] = __builtin_amdgcn_mfma_f32_16x16x32_bf16(a, WH[q][kt], acc[q], 0, 0, 0);
      if (wv < 2) {
        bfrag wl = *(const bfrag*)(smem + 16384 + (16 * wv + l16) * 1024 +
                                   ((kt * 64 + qq * 16) ^ swz));
        oacc = __builtin_amdgcn_mfma_f32_16x16x32_bf16(a, wl, oacc, 0, 0, 0);
      }
    }

    // ---- E: activations, state, tagged pkt stores (fire & forget) ----
    int2v* ps = pkt + (size_t)(((t + 1) & 3) * GB + b) * PKTS_PER_GROUP;
    #pragma unroll
    for (int r = 0; r < 4; ++r) {
      float iv = fsig(acc[0][r] + bs[0]);
      float fv = fsig(acc[1][r] + bs[1]);
      float gv = ftanh(acc[2][r] + bs[2]);
      float ov = fsig(acc[3][r] + bs[3]);
      float cn = fv * c4[r] + iv * gv;
      c4[r] = cn;
      float hn = ov * ftanh(cn);
      int hb = (int)(unsigned short)f2bf(hn);
      int pu = __shfl_xor(hb, 1);
      if ((l16 & 1) == 0) {
        int2v pk;
        pk.x = (hb & 0xffff) | (pu << 16);
        pk.y = t + 1;
        gstore8_cc(ps + (m4 + r) * 256 + (32 * k + 8 * wv + (l16 >> 1)), pk);
      }
    }

    // ---- F: out[t-1] store (cached) ----
    if (t > 0 && wv < 2) {
      #pragma unroll
      for (int r = 0; r < 4; ++r)
        out[(size_t)(16 * b + m4 + r) * T_ * F_ + (size_t)(t - 1) * F_ +
            32 * k + 16 * wv + l16] = oacc[r];
    }
  }

  // ---- tail: out[T-1] from h_T (slot T_&3 == 0, tag T_) ----
  {
    const int2v* pp = pkt + (size_t)((T_ & 3) * GB + b) * PKTS_PER_GROUP + tid;
    int2v pv[16];
    while (true) {
      #pragma unroll
      for (int j = 0; j < 16; ++j) pv[j] = gload8_cc(pp + j * 256);
      vm_drain();
      bool ok = true;
      #pragma unroll
      for (int j = 0; j < 16; ++j) ok &= (pv[j].y == T_);
      if (__all(ok)) break;
      __builtin_amdgcn_s_sleep(2);
    }
    __syncthreads();
    #pragma unroll
    for (int j = 0; j < 16; ++j)
      *(int*)(smem + j * 1024 + ((tid * 4) ^ ((j & 7) << 4))) = pv[j].x;
    __syncthreads();

    if (wv < 2) {
      f32x4 oacc = {blc, blc, blc, blc};
      #pragma unroll
      for (int kt = 0; kt < 16; ++kt) {
        bfrag a  = *(const bfrag*)(smem + l16 * 1024 + ((kt * 64 + qq * 16) ^ swz));
        bfrag wl = *(const bfrag*)(smem + 16384 + (16 * wv + l16) * 1024 +
                                   ((kt * 64 + qq * 16) ^ swz));
        oacc = __builtin_amdgcn_mfma_f32_16x16x32_bf16(a, wl, oacc, 0, 0, 0);
      }
      #pragma unroll
      for (int r = 0; r < 4; ++r)
        out[(size_t)(16 * b + m4 + r) * T_ * F_ + (size_t)(T_ - 1) * F_ +
            32 * k + 16 * wv + l16] = oacc[r];
    }
  }
}

extern "C" void kernel_launch(void* const* d_in, const int* in_sizes, int n_in,
                              void* d_out, int out_size, void* d_ws, size_t ws_size,
                              hipStream_t stream) {
  const float* z    = (const float*)d_in[0];
  const float* x    = (const float*)d_in[1];
  const float* Wih  = (const float*)d_in[2];
  const float* Whh  = (const float*)d_in[3];
  const float* bih  = (const float*)d_in[4];
  const float* bhh  = (const float*)d_in[5];
  const float* Wlin = (const float*)d_in[6];
  const float* blin = (const float*)d_in[7];
  float* out = (float*)d_out;

  int2v* pkt  = (int2v*)d_ws;                          // 512 KB
  int*   expb = (int*)((char*)d_ws + 600 * 1024);      // 32 KB experiment region

  lstm_init<<<64, 256, 0, stream>>>(z, (unsigned long long*)d_ws, expb);
  exp_mall_pp<<<2,  64, 0, stream>>>(expb);                       // [0,64)
  exp_b64    <<<64, 64, 0, stream>>>(expb + 64);                  // [64,1088)
  exp_l2_pp  <<<9,  64, 0, stream>>>(expb + 1088);                // [1088,1152)
  exp_pp_flood<<<64,64, 0, stream>>>(expb + 1152, expb + 1216);   // [1152,2240)
  lstm_persist<<<NWG, 256, 0, stream>>>(x, Wih, Whh, bih, bhh, Wlin, blin, out, pkt);
}

// Round 9
// 14169.099 us; speedup vs baseline: 2.7310x; 2.5780x over previous
//
#include <hip/hip_runtime.h>
#include <hip/hip_bf16.h>

#define B_   64
#define T_   2048
#define F_   256
#define H_   512
#define GB   4                    // batch groups (16 rows each)
#define GG   8                    // gate-split WGs per group
#define NWG  (GB*GG)              // 32
#define PAYD 4096                 // payload dwords per group: 16 rows * 256 pairs

typedef __attribute__((ext_vector_type(8))) short bfrag;   // 8 bf16 (MFMA A/B)
typedef __attribute__((ext_vector_type(4))) int   int4v;
typedef __attribute__((ext_vector_type(4))) float f32x4;
typedef __attribute__((ext_vector_type(4))) float float4_t;

__device__ __forceinline__ float fsig(float x)  { return 1.0f / (1.0f + __expf(-x)); }
__device__ __forceinline__ float ftanh(float x) { return 2.0f / (1.0f + __expf(-2.0f * x)) - 1.0f; }
__device__ __forceinline__ short f2bf(float f) {
  __hip_bfloat16 h = __float2bfloat16(f);
  return __builtin_bit_cast(short, h);
}

// ---- coherence-point (sc0 sc1: bypass L1+L2, serviced at MALL) ----
__device__ __forceinline__ int gload4_cc(const void* p) {
  int r;
  asm volatile("global_load_dword %0, %1, off sc0 sc1" : "=v"(r) : "v"(p));
  return r;
}
__device__ __forceinline__ void gstore4_cc(void* p, int d) {
  asm volatile("global_store_dword %0, %1, off sc0 sc1" :: "v"(p), "v"(d));
}
__device__ __forceinline__ int gload_flag(const void* p) {
  int r;
  asm volatile("global_load_dword %0, %1, off sc0 sc1\n\ts_waitcnt vmcnt(0)"
               : "=v"(r) : "v"(p) : "memory");
  return r;
}
__device__ __forceinline__ void vm_drain() {
  asm volatile("s_waitcnt vmcnt(0)" ::: "memory");
  __builtin_amdgcn_sched_barrier(0);   // rule #18
}

// ---------------- init: h0 payload into buf0, flags = 0 ----------------
__global__ void lstm_init(const float* __restrict__ z, int* __restrict__ pay,
                          int* __restrict__ flags) {
  int i = blockIdx.x * blockDim.x + threadIdx.x;     // 0..16383
  if (i < GB * 16) flags[i] = 0;
  int g  = i >> 12;            // group
  int p  = i & 4095;           // payload dword within group
  int j  = p >> 8;             // row within group
  int pr = p & 255;            // col pair
  int row = 16 * g + j;
  int lo = (int)((unsigned)(unsigned short)f2bf(z[(size_t)row * H_ + 2 * pr])
         | ((unsigned)(unsigned short)f2bf(z[(size_t)row * H_ + 2 * pr + 1]) << 16));
  pay[(size_t)g * PAYD + p] = lo;                    // parity-0 buffer
}

// ---------------- persistent LSTM, batch-grouped, flag-gated ----------------
// WG(b,k): batch rows [16b,16b+16), h-cols [64k,64k+64), out-cols [32k,32k+32).
// Protocol: payload dwords {2 bf16} ping-pong by parity; flags[b][k] monotonic
// step counters. Producer: payload stores -> vm_drain -> __syncthreads ->
// flag = t+1. Consumer: spin on its group's 8 flags (4B each, ~nothing), then
// read payload ONCE (16KB). 2 buffers suffice: a member's flag t+1 certifies
// its h_t payload READ completed, so the h_{t+2} write (same parity as h_t)
// cannot race it. UC bytes/step ~576KB (vs 4MB in R2-R4, ~3MB+ spin in R5).
__global__ void __launch_bounds__(256, 1)
lstm_persist(const float* __restrict__ x,
             const float* __restrict__ Wih,  const float* __restrict__ Whh,
             const float* __restrict__ bih,  const float* __restrict__ bhh,
             const float* __restrict__ Wlin, const float* __restrict__ blin,
             float* __restrict__ out, int* __restrict__ pay,
             int* __restrict__ flags)
{
  __shared__ char smem[49152];   // [0,16K): h-tile [16][512]bf16 swz; [16K,48K): W_lin slice

  const int wg  = blockIdx.x;
  const int b   = wg >> 3;
  const int k   = wg & 7;
  const int tid = threadIdx.x;
  const int wv  = tid >> 6;
  const int l   = tid & 63;
  const int l16 = l & 15;
  const int qq  = l >> 4;
  const int swz = (l16 & 7) << 4;
  const int m4  = qq << 2;                 // D row base (+reg)

  // ---- stage W_lin slice (cols 32k..32k+32, K=512) to LDS, swizzled ----
  {
    const int oc = tid >> 3;               // 0..31
    const float* src = Wlin + (size_t)(32 * k + oc) * H_ + (tid & 7) * 64;
    char* dst = smem + 16384 + oc * 1024;
    #pragma unroll
    for (int i = 0; i < 8; ++i) {
      bfrag tmp;
      #pragma unroll
      for (int e = 0; e < 8; ++e) tmp[e] = f2bf(src[i * 8 + e]);
      *(int4v*)(dst + ((((tid & 7) * 128) + i * 16) ^ ((oc & 7) << 4))) =
          __builtin_bit_cast(int4v, tmp);
    }
  }

  // ---- persistent weight fragments in VGPR ----
  bfrag WH[4][16];   // W_hh: gate q, k-tile kt
  bfrag WI[4][8];    // W_ih
  float bs[4];
  #pragma unroll
  for (int q = 0; q < 4; ++q) {
    const int grow = q * H_ + k * 64 + wv * 16 + l16;   // this lane's gate row
    #pragma unroll
    for (int kt = 0; kt < 16; ++kt) {
      const float* s = Whh + (size_t)grow * H_ + kt * 32 + qq * 8;
      bfrag w;
      #pragma unroll
      for (int e = 0; e < 8; ++e) w[e] = f2bf(s[e]);
      WH[q][kt] = w;
    }
    #pragma unroll
    for (int kt = 0; kt < 8; ++kt) {
      const float* s = Wih + (size_t)grow * F_ + kt * 32 + qq * 8;
      bfrag w;
      #pragma unroll
      for (int e = 0; e < 8; ++e) w[e] = f2bf(s[e]);
      WI[q][kt] = w;
    }
    bs[q] = bih[grow] + bhh[grow];
  }
  const float blc = (wv < 2) ? blin[32 * k + 16 * wv + l16] : 0.f;

  float c4[4] = {0.f, 0.f, 0.f, 0.f};
  __syncthreads();   // W_lin staged

  const int* myflags = flags + b * 16;     // 8 member flags, one 64B line

  for (int t = 0; t < T_; ++t) {
    // ---- A: x-part of gates (h-independent shadow work, absorbs skew) ----
    f32x4 acc[4] = {{0,0,0,0},{0,0,0,0},{0,0,0,0},{0,0,0,0}};
    {
      const float* xr = x + ((size_t)(16 * b + l16) * T_ + t) * F_ + qq * 8;
      #pragma unroll
      for (int kt = 0; kt < 8; ++kt) {
        float4_t xa = *(const float4_t*)(xr + kt * 32);
        float4_t xb = *(const float4_t*)(xr + kt * 32 + 4);
        bfrag a;
        #pragma unroll
        for (int e = 0; e < 4; ++e) { a[e] = f2bf(xa[e]); a[4 + e] = f2bf(xb[e]); }
        #pragma unroll
        for (int q = 0; q < 4; ++q)
          acc[q] = __builtin_amdgcn_mfma_f32_16x16x32_bf16(a, WI[q][kt], acc[q], 0, 0, 0);
      }
    }

    // ---- B: spin on 8 group flags (4B each), then read payload ONCE ----
    if (t > 0) {
      while (true) {
        int v = gload_flag(&myflags[l & 7]);
        if (__all(v >= t)) break;
        __builtin_amdgcn_s_sleep(1);
      }
      __builtin_amdgcn_sched_barrier(0);
    }
    const int* pp = pay + (size_t)((t & 1) * GB + b) * PAYD + tid;
    int pv[16];
    #pragma unroll
    for (int j = 0; j < 16; ++j) pv[j] = gload4_cc(pp + j * 256);
    vm_drain();
    __syncthreads();    // all waves done with prior iter's LDS reads

    // ---- C: build h-tile in LDS (swizzled) ----
    #pragma unroll
    for (int j = 0; j < 16; ++j)
      *(int*)(smem + j * 1024 + ((tid * 4) ^ ((j & 7) << 4))) = pv[j];
    __syncthreads();

    // ---- D: gates h-part + fused out[t-1] (waves 0,1 own the 2 out n-tiles) ----
    f32x4 oacc = {blc, blc, blc, blc};
    #pragma unroll
    for (int kt = 0; kt < 16; ++kt) {
      bfrag a = *(const bfrag*)(smem + l16 * 1024 + ((kt * 64 + qq * 16) ^ swz));
      #pragma unroll
      for (int q = 0; q < 4; ++q)
        acc[q] = __builtin_amdgcn_mfma_f32_16x16x32_bf16(a, WH[q][kt], acc[q], 0, 0, 0);
      if (wv < 2) {
        bfrag wl = *(const bfrag*)(smem + 16384 + (16 * wv + l16) * 1024 +
                                   ((kt * 64 + qq * 16) ^ swz));
        oacc = __builtin_amdgcn_mfma_f32_16x16x32_bf16(a, wl, oacc, 0, 0, 0);
      }
    }

    // ---- E: activations, state, payload stores -> drain -> barrier -> flag ----
    int* ps = pay + (size_t)(((t + 1) & 1) * GB + b) * PAYD;
    #pragma unroll
    for (int r = 0; r < 4; ++r) {
      float iv = fsig(acc[0][r] + bs[0]);
      float fv = fsig(acc[1][r] + bs[1]);
      float gv = ftanh(acc[2][r] + bs[2]);
      float ov = fsig(acc[3][r] + bs[3]);
      float cn = fv * c4[r] + iv * gv;
      c4[r] = cn;
      float hn = ov * ftanh(cn);
      int hb = (int)(unsigned short)f2bf(hn);
      int pu = __shfl_xor(hb, 1);
      if ((l16 & 1) == 0) {
        int packed = (hb & 0xffff) | (pu << 16);
        gstore4_cc(ps + (m4 + r) * 256 + (32 * k + 8 * wv + (l16 >> 1)), packed);
      }
    }
    vm_drain();         // this wave's payload stores completed at MALL
    __syncthreads();    // all 4 waves done
    if (tid == 0)
      gstore4_cc((void*)&flags[b * 16 + k], t + 1);

    // ---- F: out[t-1] store (cached, off critical path) ----
    if (t > 0 && wv < 2) {
      #pragma unroll
      for (int r = 0; r < 4; ++r)
        out[(size_t)(16 * b + m4 + r) * T_ * F_ + (size_t)(t - 1) * F_ +
            32 * k + 16 * wv + l16] = oacc[r];
    }
  }

  // ---- tail: out[T-1] from h_T (parity 0, flags >= T_) ----
  {
    while (true) {
      int v = gload_flag(&myflags[l & 7]);
      if (__all(v >= T_)) break;
      __builtin_amdgcn_s_sleep(1);
    }
    __builtin_amdgcn_sched_barrier(0);

    const int* pp = pay + (size_t)((T_ & 1) * GB + b) * PAYD + tid;
    int pv[16];
    #pragma unroll
    for (int j = 0; j < 16; ++j) pv[j] = gload4_cc(pp + j * 256);
    vm_drain();
    __syncthreads();
    #pragma unroll
    for (int j = 0; j < 16; ++j)
      *(int*)(smem + j * 1024 + ((tid * 4) ^ ((j & 7) << 4))) = pv[j];
    __syncthreads();

    if (wv < 2) {
      f32x4 oacc = {blc, blc, blc, blc};
      #pragma unroll
      for (int kt = 0; kt < 16; ++kt) {
        bfrag a  = *(const bfrag*)(smem + l16 * 1024 + ((kt * 64 + qq * 16) ^ swz));
        bfrag wl = *(const bfrag*)(smem + 16384 + (16 * wv + l16) * 1024 +
                                   ((kt * 64 + qq * 16) ^ swz));
        oacc = __builtin_amdgcn_mfma_f32_16x16x32_bf16(a, wl, oacc, 0, 0, 0);
      }
      #pragma unroll
      for (int r = 0; r < 4; ++r)
        out[(size_t)(16 * b + m4 + r) * T_ * F_ + (size_t)(T_ - 1) * F_ +
            32 * k + 16 * wv + l16] = oacc[r];
    }
  }
}

extern "C" void kernel_launch(void* const* d_in, const int* in_sizes, int n_in,
                              void* d_out, int out_size, void* d_ws, size_t ws_size,
                              hipStream_t stream) {
  const float* z    = (const float*)d_in[0];
  const float* x    = (const float*)d_in[1];
  const float* Wih  = (const float*)d_in[2];
  const float* Whh  = (const float*)d_in[3];
  const float* bih  = (const float*)d_in[4];
  const float* bhh  = (const float*)d_in[5];
  const float* Wlin = (const float*)d_in[6];
  const float* blin = (const float*)d_in[7];
  float* out = (float*)d_out;

  int* pay   = (int*)d_ws;                              // 2 * 4 * 4096 * 4B = 128 KB
  int* flags = (int*)((char*)d_ws + 192 * 1024);        // 64 ints (16/group, padded)

  lstm_init<<<64, 256, 0, stream>>>(z, pay, flags);
  lstm_persist<<<NWG, 256, 0, stream>>>(x, Wih, Whh, bih, bhh, Wlin, blin, out,
                                        pay, flags);
}